// Round 1
// baseline (204.755 us; speedup 1.0000x reference)
//
#include <hip/hip_runtime.h>

typedef float f32x4 __attribute__((ext_vector_type(4)));
typedef short bf16x8 __attribute__((ext_vector_type(8)));

#define B_TOT 8192
#define D_ 64
#define K_ 16
#define H_ 5
#define IN_ 256

__device__ __forceinline__ unsigned short f2bf(float f){
  unsigned int u = __float_as_uint(f);
  u += 0x7fffu + ((u >> 16) & 1u);   // round-to-nearest-even
  return (unsigned short)(u >> 16);
}

// ---------------- pack per-j weight matrix: Wpack[j][192][256] bf16 ----------------
// rows 0..79  : W1[k][j][h][:]  (r = k*5+h)
// rows 80..95 : Wx[k][j][:]
// rows 96..175: sW1
// rows 176..191: sWx
__global__ void pack_weights_kernel(const float* __restrict__ W1,
                                    const float* __restrict__ Wx,
                                    const float* __restrict__ sW1,
                                    const float* __restrict__ sWx,
                                    unsigned short* __restrict__ Wpack){
  int j = blockIdx.x;       // 64
  int r = blockIdx.y;       // 192
  int c = threadIdx.x;      // 256
  const float* src;
  if (r < 80)      { int k = r/5, h = r%5;            src = W1  + (((k*D_ + j)*H_ + h)*IN_); }
  else if (r < 96) { int k = r-80;                    src = Wx  + ((k*D_ + j)*IN_); }
  else if (r < 176){ int rr = r-96; int k=rr/5,h=rr%5; src = sW1 + (((k*D_ + j)*H_ + h)*IN_); }
  else             { int k = r-176;                   src = sWx + ((k*D_ + j)*IN_); }
  Wpack[((j*192 + r) << 8) + c] = f2bf(src[c]);
}

// ---------------- masked-softmax target weights: wout[j][i][k] ----------------
__global__ void compute_w_kernel(const float* __restrict__ targets, float* __restrict__ wout){
  int j = blockIdx.x;
  int i = threadIdx.x;      // 64 threads, first 16 active
  if (i >= K_) return;
  float base[K_];
  base[0] = (i == 0) ? 1.f : 0.f;
  for (int c = 1; c <= i; ++c)
    base[c] = targets[(j*K_ + i)*(K_-1) + (c-1)] + ((c == i) ? 1.f : 0.f);
  float mx = base[0];
  for (int c = 1; c <= i; ++c) mx = fmaxf(mx, base[c]);
  float e[K_]; float s = 0.f;
  for (int c = 0; c <= i; ++c){ e[c] = expf(base[c] - mx); s += e[c]; }
  float inv = 1.f / s;
  for (int c = 0; c < K_; ++c)
    wout[(j*K_ + i)*K_ + c] = (c <= i) ? e[c]*inv : 0.f;
}

// ---------------- main fused kernel ----------------
// grid (16 jg, 128 btile), 256 threads (4 waves). BM=64 rows, 192 cols, K=256 in 2 chunks of 128.
// LDS union: staging { A[64][128] bf16 swz (16KB) | B[192][128] bf16 swz (48KB) }
//            epilogue { G[64][197] f32 | nn[64][17] | w_s[256] | xv_s[64] }
__global__ __launch_bounds__(256, 2)
void main_kernel(const float* __restrict__ x_values,
                 const float* __restrict__ x_inputs,
                 const unsigned short* __restrict__ Wpack,
                 const float* __restrict__ wsm,
                 const float* __restrict__ b1, const float* __restrict__ Wh, const float* __restrict__ b2,
                 const float* __restrict__ sb1, const float* __restrict__ sWh, const float* __restrict__ sb2,
                 float* __restrict__ partial){
  __shared__ __align__(16) char sm[65536];
  float* G    = (float*)sm;               // [64][197] = 50432 B
  float* nn   = (float*)(sm + 50432);     // [64][17]  = 4352 B
  float* w_s  = (float*)(sm + 54784);     // [256]     = 1024 B
  float* xv_s = (float*)(sm + 55808);     // [64]      = 256 B

  const int t    = threadIdx.x;
  const int jg   = blockIdx.x;
  const int b0   = blockIdx.y * 64;
  const int lane = t & 63;
  const int wv   = t >> 6;
  const int q    = wv;        // epilogue k/i quarter
  const int r    = t & 63;    // epilogue row

  float accnll[4] = {0.f, 0.f, 0.f, 0.f};

  for (int jj = 0; jj < 4; ++jj){
    const int j = jg*4 + jj;
    f32x4 acc[4][3];
    #pragma unroll
    for (int m = 0; m < 4; ++m)
      #pragma unroll
      for (int n = 0; n < 3; ++n) acc[m][n] = (f32x4){0.f,0.f,0.f,0.f};

    #pragma unroll
    for (int kc = 0; kc < 2; ++kc){
      // ---- stage A: 64x128 f32 -> bf16, swizzled ----
      {
        const int cb = t & 15, r0 = t >> 4;
        #pragma unroll
        for (int p = 0; p < 4; ++p){
          const int row = p*16 + r0;
          const float* src = x_inputs + (((size_t)(b0 + row)*D_ + j) << 8) + kc*128 + cb*8;
          f32x4 v0 = *(const f32x4*)(src);
          f32x4 v1 = *(const f32x4*)(src + 4);
          bf16x8 o;
          o[0]=f2bf(v0[0]); o[1]=f2bf(v0[1]); o[2]=f2bf(v0[2]); o[3]=f2bf(v0[3]);
          o[4]=f2bf(v1[0]); o[5]=f2bf(v1[1]); o[6]=f2bf(v1[2]); o[7]=f2bf(v1[3]);
          *(bf16x8*)(sm + row*256 + ((cb*16) ^ ((row & 7) << 4))) = o;
        }
      }
      // ---- stage B: 192x128 bf16 from Wpack, swizzled ----
      #pragma unroll
      for (int c2 = 0; c2 < 12; ++c2){
        const int idx = c2*256 + t;
        const int n = idx >> 4, cb = idx & 15;
        const unsigned short* src = Wpack + (((size_t)j*192 + n) << 8) + kc*128 + cb*8;
        bf16x8 v = *(const bf16x8*)src;
        *(bf16x8*)(sm + 16384 + n*256 + ((cb*16) ^ ((n & 7) << 4))) = v;
      }
      __syncthreads();
      // ---- MFMA: 4 k-steps x (4m x 3n) ----
      #pragma unroll
      for (int kk = 0; kk < 4; ++kk){
        const int colb = kk*64 + ((lane >> 4) << 4);
        bf16x8 a[4], bfr[3];
        #pragma unroll
        for (int m = 0; m < 4; ++m){
          const int row = m*16 + (lane & 15);
          a[m] = *(const bf16x8*)(sm + row*256 + (colb ^ ((row & 7) << 4)));
        }
        #pragma unroll
        for (int n = 0; n < 3; ++n){
          const int row = wv*48 + n*16 + (lane & 15);
          bfr[n] = *(const bf16x8*)(sm + 16384 + row*256 + (colb ^ ((row & 7) << 4)));
        }
        #pragma unroll
        for (int m = 0; m < 4; ++m)
          #pragma unroll
          for (int n = 0; n < 3; ++n)
            acc[m][n] = __builtin_amdgcn_mfma_f32_16x16x32_bf16(a[m], bfr[n], acc[m][n], 0, 0, 0);
      }
      __syncthreads();
    }
    // ---- write G (C-layout: col=lane&15, row=(lane>>4)*4+e), stage w, xv ----
    #pragma unroll
    for (int m = 0; m < 4; ++m){
      const int rbase = m*16 + ((lane >> 4) << 2);
      #pragma unroll
      for (int n = 0; n < 3; ++n){
        const int col = wv*48 + n*16 + (lane & 15);
        #pragma unroll
        for (int e = 0; e < 4; ++e)
          G[(rbase + e)*197 + col] = acc[m][n][e];
      }
    }
    w_s[t] = wsm[(j << 8) + t];
    if (t < 64) xv_s[t] = x_values[(size_t)(b0 + t)*D_ + j];
    __syncthreads();
    // ---- E1: per (row, k) nll_node ----
    {
      const float xv = xv_s[r];
      #pragma unroll
      for (int kk = 0; kk < 4; ++kk){
        const int k = q*4 + kk;
        float mean = b2[j*K_ + k] + G[r*197 + 80 + k];
        #pragma unroll
        for (int h = 0; h < H_; ++h){
          float v = G[r*197 + k*H_ + h] + b1[(j*K_ + k)*H_ + h];
          v = (v > 0.f) ? v : 0.2f*v;
          mean += v * Wh[(k*D_ + j)*H_ + h];
        }
        float sh = sb2[j*K_ + k] + G[r*197 + 176 + k];
        #pragma unroll
        for (int h = 0; h < H_; ++h){
          float v = G[r*197 + 96 + k*H_ + h] + sb1[(j*K_ + k)*H_ + h];
          v = (v > 0.f) ? v : 0.2f*v;
          sh += v * sWh[(k*D_ + j)*H_ + h];
        }
        float sg  = 10.f / (1.f + expf(-sh));
        float var = fmaxf(sg*sg, 1e-6f);
        float d   = xv - mean;
        nn[r*17 + k] = 0.5f*(logf(var) + d*d/var);
      }
    }
    __syncthreads();
    // ---- E2: nll partial accumulate over this j ----
    #pragma unroll
    for (int ii = 0; ii < 4; ++ii){
      const int i = q*4 + ii;
      float s = 0.f;
      #pragma unroll
      for (int k = 0; k < K_; ++k) s += nn[r*17 + k] * w_s[i*K_ + k];
      accnll[ii] += s;
    }
    __syncthreads();
  }
  #pragma unroll
  for (int ii = 0; ii < 4; ++ii)
    partial[((size_t)jg*B_TOT + b0 + r)*K_ + q*4 + ii] = accnll[ii];
}

// ---------------- final reduce over 16 j-groups ----------------
__global__ void reduce_kernel(const float* __restrict__ partial, float* __restrict__ out){
  int idx = blockIdx.x*256 + threadIdx.x;   // 131072 total
  float s = 0.f;
  #pragma unroll
  for (int g = 0; g < 16; ++g) s += partial[(size_t)g*(B_TOT*K_) + idx];
  out[idx] = s;
}

extern "C" void kernel_launch(void* const* d_in, const int* in_sizes, int n_in,
                              void* d_out, int out_size, void* d_ws, size_t ws_size,
                              hipStream_t stream){
  const float* x_values = (const float*)d_in[0];
  const float* x_inputs = (const float*)d_in[1];
  const float* targets  = (const float*)d_in[2];
  const float* W1  = (const float*)d_in[3];
  const float* b1  = (const float*)d_in[4];
  const float* Wh  = (const float*)d_in[5];
  const float* Wx  = (const float*)d_in[6];
  const float* b2  = (const float*)d_in[7];
  const float* sW1 = (const float*)d_in[8];
  const float* sb1 = (const float*)d_in[9];
  const float* sWh = (const float*)d_in[10];
  const float* sWx = (const float*)d_in[11];
  const float* sb2 = (const float*)d_in[12];
  (void)in_sizes; (void)n_in; (void)out_size; (void)ws_size;

  char* ws = (char*)d_ws;
  unsigned short* Wpack = (unsigned short*)ws;           // 6,291,456 B
  float* wsm     = (float*)(ws + 6291456);               // 65,536 B
  float* partial = (float*)(ws + 6356992);               // 8,388,608 B
  float* out = (float*)d_out;

  pack_weights_kernel<<<dim3(64, 192), 256, 0, stream>>>(W1, Wx, sW1, sWx, Wpack);
  compute_w_kernel<<<dim3(64), 64, 0, stream>>>(targets, wsm);
  main_kernel<<<dim3(16, 128), 256, 0, stream>>>(x_values, x_inputs, Wpack, wsm,
                                                 b1, Wh, b2, sb1, sWh, sb2, partial);
  reduce_kernel<<<dim3(512), 256, 0, stream>>>(partial, out);
}